// Round 3
// baseline (20906.950 us; speedup 1.0000x reference)
//
#include <hip/hip_runtime.h>
#include <stdint.h>

#define NN 4096
#define TT 256
#define KK 16
#define NB 256
#define NTH 1024

typedef unsigned short u16;
typedef unsigned int u32;

// ws layout (bytes):
//   tempT : float [TT*NN]   @ 0         (4 MiB)
//   outs  : float [TT*NN]   @ 4194304   (4 MiB)
//   hb    : u16   [TT*NN]   @ 8388608   (2 MiB)  bf16 h per step
//   flags : int   [TT*NB]   @ 10485760  (256 KiB)
//   misc  : int   [16]      @ 10747904  (arrive @0, abort @8)

__device__ __forceinline__ u32 f2bf(float f) {
    u32 u = __float_as_uint(f);
    return (u + 0x7fffu + ((u >> 16) & 1u)) >> 16; // RNE
}
__device__ __forceinline__ float lo2f(u32 u) { return __uint_as_float(u << 16); }
__device__ __forceinline__ float hi2f(u32 u) { return __uint_as_float(u & 0xFFFF0000u); }

__global__ void prep_tempt(const float* __restrict__ x, const float* __restrict__ w,
                           float* __restrict__ tempT) {
    int idx = blockIdx.x * blockDim.x + threadIdx.x;
    int t = idx >> 12;
    int n = idx & (NN - 1);
    const float4* xp = (const float4*)(x + ((size_t)n * TT + t) * 8);
    float4 a = xp[0], b = xp[1];
    tempT[idx] = a.x * w[0] + a.y * w[1] + a.z * w[2] + a.w * w[3]
               + b.x * w[4] + b.y * w[5] + b.z * w[6] + b.w * w[7];
}

__global__ void init_ws(int* __restrict__ flags, int* __restrict__ misc) {
    int i = blockIdx.x * blockDim.x + threadIdx.x;
    if (i < TT * NB) flags[i] = 0;
    if (i < 16) misc[i] = 0;
}

__global__ __launch_bounds__(NTH) void persist(
    const float* __restrict__ M, const float* __restrict__ xi,
    const float* __restrict__ hidden, const float* __restrict__ tempT,
    float* __restrict__ outs, u16* __restrict__ hb,
    int* __restrict__ flags, int* __restrict__ misc)
{
    __shared__ u32 hs[NN / 2];      // 8 KiB: h_t as packed bf16 pairs
    __shared__ u32 pad[20480];      // 80 KiB: occupancy limiter -> 1 block/CU

    int tid = threadIdx.x, bid = blockIdx.x;
    int w = tid >> 6, l = tid & 63;
    int row = bid * 16 + w;

    pad[tid] = tid;                              // keep pad alive
    asm volatile("" :: "v"(pad[(tid + 7) & 20479]));

    float scale = expf(xi[0]);

    // ---- A row -> 32 packed-bf16 VGPRs (lane l: elems r*512 + l*8 + 0..7) ----
    u32 Areg[32];
    {
        const float4* Mp = (const float4*)(M + (size_t)row * NN);
#pragma unroll
        for (int r = 0; r < 8; r++) {
            float4 va = Mp[r * 128 + l * 2];
            float4 vb = Mp[r * 128 + l * 2 + 1];
            Areg[r * 4 + 0] = f2bf(va.x * scale) | (f2bf(va.y * scale) << 16);
            Areg[r * 4 + 1] = f2bf(va.z * scale) | (f2bf(va.w * scale) << 16);
            Areg[r * 4 + 2] = f2bf(vb.x * scale) | (f2bf(vb.y * scale) << 16);
            Areg[r * 4 + 3] = f2bf(vb.z * scale) | (f2bf(vb.w * scale) << 16);
        }
    }
    // ---- bias preload: step t -> reg (t>>6), lane (t&63) ----
    float b0 = tempT[(size_t)(l)       * NN + row];
    float b1 = tempT[(size_t)(l + 64)  * NN + row];
    float b2 = tempT[(size_t)(l + 128) * NN + row];
    float b3 = tempT[(size_t)(l + 192) * NN + row];

    // ---- stage h0 ----
    {
        float4 v = ((const float4*)hidden)[tid];
        hs[tid * 2]     = f2bf(v.x) | (f2bf(v.y) << 16);
        hs[tid * 2 + 1] = f2bf(v.z) | (f2bf(v.w) << 16);
    }
    __syncthreads();

    int* arrive = misc;
    int* abortf = misc + 8;
    if (tid == 0) {
        __hip_atomic_fetch_add(arrive, 1, __ATOMIC_RELAXED, __HIP_MEMORY_SCOPE_AGENT);
        int spins = 0;
        while (__hip_atomic_load(arrive, __ATOMIC_RELAXED, __HIP_MEMORY_SCOPE_AGENT) < NB) {
            if (++spins > (1 << 22)) {   // bounded: ~<1 s then abort, never hang
                __hip_atomic_store(abortf, 1, __ATOMIC_RELAXED, __HIP_MEMORY_SCOPE_AGENT);
                break;
            }
        }
    }
    __syncthreads();

    for (int t = 0; t < TT; t++) {
        // ---- y = A_row . h + b ----
        float acc = 0.f;
#pragma unroll
        for (int r = 0; r < 8; r++) {
            uint4 h4 = *(const uint4*)&hs[r * 256 + l * 4];   // ds_read_b128
            u32 a0 = Areg[r * 4], a1 = Areg[r * 4 + 1];
            u32 a2 = Areg[r * 4 + 2], a3 = Areg[r * 4 + 3];
            acc = fmaf(lo2f(a0), lo2f(h4.x), acc);
            acc = fmaf(hi2f(a0), hi2f(h4.x), acc);
            acc = fmaf(lo2f(a1), lo2f(h4.y), acc);
            acc = fmaf(hi2f(a1), hi2f(h4.y), acc);
            acc = fmaf(lo2f(a2), lo2f(h4.z), acc);
            acc = fmaf(hi2f(a2), hi2f(h4.z), acc);
            acc = fmaf(lo2f(a3), lo2f(h4.w), acc);
            acc = fmaf(hi2f(a3), hi2f(h4.w), acc);
        }
#pragma unroll
        for (int off = 32; off; off >>= 1) acc += __shfl_xor(acc, off, 64);

        float bq = (t < 128) ? ((t < 64) ? b0 : b1) : ((t < 192) ? b2 : b3);
        float y = acc + __shfl(bq, t & 63, 64);

        if (l == 0) {
            __builtin_nontemporal_store(y, &outs[(size_t)t * NN + row]);
            hb[(size_t)t * NN + row] = (u16)f2bf(y);
        }
        __builtin_amdgcn_fence(__ATOMIC_RELEASE, "agent");  // wbl2: push hb to MALL
        __syncthreads();                                    // all rows stored+fenced
        if (tid == 0)
            __hip_atomic_store(&flags[t * NB + bid], 1,
                               __ATOMIC_RELEASE, __HIP_MEMORY_SCOPE_AGENT);
        if (t == TT - 1) break;

        // ---- wait for all 256 blocks' h_{t+1} (wave 0 polls, bounded) ----
        if (w == 0) {
            int give = 0;
            if (l == 0)
                give = __hip_atomic_load(abortf, __ATOMIC_RELAXED, __HIP_MEMORY_SCOPE_AGENT);
            give = __shfl(give, 0, 64);
            if (!give) {
                const int* fl = flags + t * NB;
                int rounds = 0;
                for (;;) {
                    int ok = (__hip_atomic_load(&fl[l],       __ATOMIC_ACQUIRE, __HIP_MEMORY_SCOPE_AGENT) != 0)
                           & (__hip_atomic_load(&fl[l + 64],  __ATOMIC_ACQUIRE, __HIP_MEMORY_SCOPE_AGENT) != 0)
                           & (__hip_atomic_load(&fl[l + 128], __ATOMIC_ACQUIRE, __HIP_MEMORY_SCOPE_AGENT) != 0)
                           & (__hip_atomic_load(&fl[l + 192], __ATOMIC_ACQUIRE, __HIP_MEMORY_SCOPE_AGENT) != 0);
                    if (__all(ok)) break;
                    if (++rounds > (1 << 20)) {   // bounded: abort, never hang
                        __hip_atomic_store(abortf, 1, __ATOMIC_RELAXED, __HIP_MEMORY_SCOPE_AGENT);
                        break;
                    }
                }
            }
        }
        __syncthreads();
        __builtin_amdgcn_fence(__ATOMIC_ACQUIRE, "agent");
        // reload h_{t+1}: fresh addresses (t-indexed) -> no stale-line hazard
        ((uint2*)hs)[tid] = *((const uint2*)(hb + (size_t)t * NN) + tid);
        __syncthreads();
    }
}

__global__ void emit(const float* __restrict__ outs, float* __restrict__ out) {
    int idx = blockIdx.x * blockDim.x + threadIdx.x;
    if (idx < 240 * NN) {
        int tt = idx >> 12;
        int n  = idx & (NN - 1);
        out[(size_t)n * 240 + tt] = outs[(size_t)(tt + KK) * NN + n];
    } else {
        int n = idx - 240 * NN;
        out[(size_t)240 * NN + n] = outs[(size_t)(TT - 1) * NN + n];
    }
}

extern "C" void kernel_launch(void* const* d_in, const int* in_sizes, int n_in,
                              void* d_out, int out_size, void* d_ws, size_t ws_size,
                              hipStream_t stream) {
    const float* x      = (const float*)d_in[0];
    const float* hidden = (const float*)d_in[1];
    const float* M      = (const float*)d_in[2];
    const float* w      = (const float*)d_in[3];
    const float* xi     = (const float*)d_in[4];

    char* ws = (char*)d_ws;
    float* tempT = (float*)(ws);
    float* outs  = (float*)(ws + 4194304);
    u16*   hb    = (u16*)  (ws + 8388608);
    int*   flags = (int*)  (ws + 10485760);
    int*   misc  = (int*)  (ws + 10747904);
    float* out   = (float*)d_out;

    init_ws<<<NB, 256, 0, stream>>>(flags, misc);
    prep_tempt<<<(TT * NN) / 256, 256, 0, stream>>>(x, w, tempT);
    persist<<<NB, NTH, 0, stream>>>(M, xi, hidden, tempT, outs, hb, flags, misc);
    emit<<<(240 * NN + NN) / 256, 256, 0, stream>>>(outs, out);
}

// Round 4
// 1279.610 us; speedup vs baseline: 16.3385x; 16.3385x over previous
//
#include <hip/hip_runtime.h>
#include <stdint.h>

#define NN 4096
#define TT 256
#define KK 16

typedef unsigned short u16;
typedef unsigned int u32;
typedef short bf16x8 __attribute__((ext_vector_type(8)));
typedef float f32x4 __attribute__((ext_vector_type(4)));

__device__ __forceinline__ u32 f2bf(float f) {
    u32 u = __float_as_uint(f);
    return (u + 0x7fffu + ((u >> 16) & 1u)) >> 16; // RNE
}
__device__ __forceinline__ float b2f(u32 v) { return __uint_as_float(v << 16); }
__device__ __forceinline__ float lo2f(u32 u) { return __uint_as_float(u << 16); }
__device__ __forceinline__ float hi2f(u32 u) { return __uint_as_float(u & 0xFFFF0000u); }

__device__ __forceinline__ void gload16(const void* g, void* l) {
    __builtin_amdgcn_global_load_lds(
        (const __attribute__((address_space(1))) void*)g,
        (__attribute__((address_space(3))) void*)l, 16, 0, 0);
}

// ---------- prep ----------

// tempT[t][n] = sum_s x[n][t][s] * w[s]
__global__ void prep_tempt(const float* __restrict__ x, const float* __restrict__ w,
                           float* __restrict__ tempT) {
    int idx = blockIdx.x * blockDim.x + threadIdx.x;
    int t = idx >> 12;
    int n = idx & (NN - 1);
    const float4* xp = (const float4*)(x + ((size_t)n * TT + t) * 8);
    float4 a = xp[0], b = xp[1];
    tempT[idx] = a.x * w[0] + a.y * w[1] + a.z * w[2] + a.w * w[3]
               + b.x * w[4] + b.y * w[5] + b.z * w[6] + b.w * w[7];
}

// Ab = bf16(exp(xi)*M), row-major
__global__ void convA(const float* __restrict__ M, const float* __restrict__ xi,
                      u16* __restrict__ Ab) {
    int idx = blockIdx.x * blockDim.x + threadIdx.x;   // < NN*NN/4
    float s = expf(xi[0]);
    float4 v = ((const float4*)M)[idx];
    ushort4 o;
    o.x = (u16)f2bf(v.x * s); o.y = (u16)f2bf(v.y * s);
    o.z = (u16)f2bf(v.z * s); o.w = (u16)f2bf(v.w * s);
    ((ushort4*)Ab)[idx] = o;
}

// AbT[j][i] = bf16(exp(xi)*M[i][j])  (transposing convert, 64x64 tiles)
__global__ void convAT(const float* __restrict__ M, const float* __restrict__ xi,
                       u16* __restrict__ AbT) {
    __shared__ float tile[64][65];
    float s = expf(xi[0]);
    int bi = blockIdx.y * 64, bj = blockIdx.x * 64;
    int r = threadIdx.x >> 4, c4 = threadIdx.x & 15;
#pragma unroll
    for (int rr = 0; rr < 64; rr += 16) {
        float4 v = *(const float4*)(M + (size_t)(bi + rr + r) * NN + bj + c4 * 4);
        tile[rr + r][c4 * 4 + 0] = v.x; tile[rr + r][c4 * 4 + 1] = v.y;
        tile[rr + r][c4 * 4 + 2] = v.z; tile[rr + r][c4 * 4 + 3] = v.w;
    }
    __syncthreads();
#pragma unroll
    for (int rr = 0; rr < 64; rr += 16) {
        int j = rr + r;
        ushort4 o;
        o.x = (u16)f2bf(s * tile[c4 * 4 + 0][j]);
        o.y = (u16)f2bf(s * tile[c4 * 4 + 1][j]);
        o.z = (u16)f2bf(s * tile[c4 * 4 + 2][j]);
        o.w = (u16)f2bf(s * tile[c4 * 4 + 3][j]);
        *(ushort4*)(AbT + (size_t)(bj + j) * NN + bi + c4 * 4) = o;
    }
}

// bf16 transpose (for P2b -> P2bT)
__global__ void trans_bf(const u16* __restrict__ src, u16* __restrict__ dst) {
    __shared__ u16 tile[64][72];
    int bi = blockIdx.y * 64, bj = blockIdx.x * 64;
    int r = threadIdx.x >> 4, c4 = threadIdx.x & 15;
#pragma unroll
    for (int rr = 0; rr < 64; rr += 16) {
        ushort4 v = *(const ushort4*)(src + (size_t)(bi + rr + r) * NN + bj + c4 * 4);
        tile[rr + r][c4 * 4 + 0] = v.x; tile[rr + r][c4 * 4 + 1] = v.y;
        tile[rr + r][c4 * 4 + 2] = v.z; tile[rr + r][c4 * 4 + 3] = v.w;
    }
    __syncthreads();
#pragma unroll
    for (int rr = 0; rr < 64; rr += 16) {
        int j = rr + r;
        ushort4 o;
        o.x = tile[c4 * 4 + 0][j]; o.y = tile[c4 * 4 + 1][j];
        o.z = tile[c4 * 4 + 2][j]; o.w = tile[c4 * 4 + 3][j];
        *(ushort4*)(dst + (size_t)(bj + j) * NN + bi + c4 * 4) = o;
    }
}

__global__ void conv_c1Tb(const float* __restrict__ t, u16* __restrict__ o) {
    int idx = blockIdx.x * blockDim.x + threadIdx.x;  // < TT*NN/4
    float4 v = ((const float4*)t)[idx];
    ushort4 r;
    r.x = (u16)f2bf(v.x); r.y = (u16)f2bf(v.y);
    r.z = (u16)f2bf(v.z); r.w = (u16)f2bf(v.w);
    ((ushort4*)o)[idx] = r;
}

__global__ void zero_tails(float* __restrict__ a, float* __restrict__ b) {
    int i = blockIdx.x * blockDim.x + threadIdx.x;    // < 2*NN
    a[(size_t)TT * NN + i] = 0.f;
    b[(size_t)TT * NN + i] = 0.f;
}

__global__ void init_h0(const float* __restrict__ hidden, float* __restrict__ h0) {
    int i = blockIdx.x * blockDim.x + threadIdx.x;
    if (i < NN) h0[i] = hidden[i];
}

// ---------- MFMA GEMM:  C[m][n] = sum_k Ag[m][k] * Bg[n][k]  (B passed transposed) ----------
// 128x128 tile, BK=64, 4 waves (2x2 of 64x64), global_load_lds w16, XOR chunk swizzle.
__global__ __launch_bounds__(256) void gemm_bt(
    const u16* __restrict__ Ag, const u16* __restrict__ Bg, int K,
    u16* __restrict__ outB, float* __restrict__ outF,
    const float* __restrict__ shiftsrc, int shiftr, int N)
{
    __shared__ u16 As[128 * 64];
    __shared__ u16 Bs[128 * 64];
    int tid = threadIdx.x;
    int w = tid >> 6, l = tid & 63;
    int wr = w >> 1, wc = w & 1;
    int bm = blockIdx.y, bn = blockIdx.x;
    const size_t Abase = (size_t)bm * 128 * K;
    const size_t Bbase = (size_t)bn * 128 * K;

    f32x4 zf = {0.f, 0.f, 0.f, 0.f};
    f32x4 acc[4][4];
#pragma unroll
    for (int i = 0; i < 4; i++)
#pragma unroll
        for (int j = 0; j < 4; j++) acc[i][j] = zf;

    for (int kt = 0; kt < K; kt += 64) {
        // stage A-tile [128][64] and B-tile [128][64], chunk-swizzled via global src
#pragma unroll
        for (int rnd = 0; rnd < 4; rnd++) {
            int i = rnd * 256 + tid;
            int m = i >> 3, cs = i & 7;
            int cg = cs ^ (m & 7);
            gload16(Ag + Abase + (size_t)m * K + kt + cg * 8,
                    (char*)As + (rnd * 256 + w * 64) * 16);
            gload16(Bg + Bbase + (size_t)m * K + kt + cg * 8,
                    (char*)Bs + (rnd * 256 + w * 64) * 16);
        }
        __syncthreads();
#pragma unroll
        for (int kk = 0; kk < 2; kk++) {
            bf16x8 af[4], bfr[4];
#pragma unroll
            for (int mi = 0; mi < 4; mi++) {
                int ml = wr * 64 + mi * 16 + (l & 15);
                int c = (kk * 4 + (l >> 4)) ^ (ml & 7);
                af[mi] = *(const bf16x8*)((const char*)As + ml * 128 + c * 16);
            }
#pragma unroll
            for (int ni = 0; ni < 4; ni++) {
                int nl = wc * 64 + ni * 16 + (l & 15);
                int c = (kk * 4 + (l >> 4)) ^ (nl & 7);
                bfr[ni] = *(const bf16x8*)((const char*)Bs + nl * 128 + c * 16);
            }
#pragma unroll
            for (int mi = 0; mi < 4; mi++)
#pragma unroll
                for (int ni = 0; ni < 4; ni++)
                    acc[mi][ni] = __builtin_amdgcn_mfma_f32_16x16x32_bf16(
                        af[mi], bfr[ni], acc[mi][ni], 0, 0, 0);
        }
        __syncthreads();
    }
    // epilogue (C/D: col=lane&15, row=(lane>>4)*4+reg — m89-verified)
#pragma unroll
    for (int mi = 0; mi < 4; mi++)
#pragma unroll
        for (int ni = 0; ni < 4; ni++) {
            f32x4 v = acc[mi][ni];
#pragma unroll
            for (int q = 0; q < 4; q++) {
                int row = bm * 128 + wr * 64 + mi * 16 + (l >> 4) * 4 + q;
                int col = bn * 128 + wc * 64 + ni * 16 + (l & 15);
                float xv = v[q];
                if (shiftsrc) xv += shiftsrc[(size_t)(row + shiftr) * N + col];
                if (outF) outF[(size_t)row * N + col] = xv;
                if (outB) outB[(size_t)row * N + col] = (u16)f2bf(xv);
            }
        }
}

// ---------- recurrence steps ----------

// single step (seeds / fallback): hout[r] = dot(Ab[r,:], hin) + bcol[r]
__global__ __launch_bounds__(512) void step1(const u16* __restrict__ Ab,
                                             const float* __restrict__ bcol,
                                             const float* __restrict__ hin,
                                             float* __restrict__ hout) {
    __shared__ float hs[NN];
    int tid = threadIdx.x;
    {
        const float4* hp = (const float4*)hin;
        float4* sp = (float4*)hs;
        sp[tid]       = hp[tid];
        sp[tid + 512] = hp[tid + 512];
    }
    __syncthreads();
    int w = tid >> 6, l = tid & 63;
    int r = blockIdx.x * 8 + w;
    const ushort4* Mr = (const ushort4*)(Ab + (size_t)r * NN);
    const float4*  h4 = (const float4*)hs;
    float acc = 0.f;
#pragma unroll
    for (int i = 0; i < 16; i++) {
        int idx = i * 64 + l;
        ushort4 m = Mr[idx];
        float4  h = h4[idx];
        acc += b2f(m.x) * h.x + b2f(m.y) * h.y + b2f(m.z) * h.z + b2f(m.w) * h.w;
    }
#pragma unroll
    for (int off = 32; off; off >>= 1) acc += __shfl_xor(acc, off, 64);
    if (l == 0) hout[r] = acc + bcol[r];
}

// macro step: S chains, hout[c][r] = dot(P[r,:], hin[c]) + bias[c][r]
template <int S>
__global__ __launch_bounds__(512) void macro_step(
    const u16* __restrict__ P, const float* __restrict__ bias,
    const float* __restrict__ hin, float* __restrict__ hout, int cmax)
{
    __shared__ u32 hs[S * 2048];
    int tid = threadIdx.x;
#pragma unroll
    for (int c = 0; c < S; c++) {
        const float4* hp = (const float4*)(hin + c * NN);
        float4 a = hp[tid * 2], b = hp[tid * 2 + 1];
        uint4 o;
        o.x = f2bf(a.x) | (f2bf(a.y) << 16);
        o.y = f2bf(a.z) | (f2bf(a.w) << 16);
        o.z = f2bf(b.x) | (f2bf(b.y) << 16);
        o.w = f2bf(b.z) | (f2bf(b.w) << 16);
        *(uint4*)&hs[c * 2048 + tid * 4] = o;
    }
    __syncthreads();
    int w = tid >> 6, l = tid & 63;
    int r = blockIdx.x * 8 + w;
    const ushort4* Pr = (const ushort4*)(P + (size_t)r * NN);
    float accv[S];
#pragma unroll
    for (int c = 0; c < S; c++) accv[c] = 0.f;
#pragma unroll
    for (int i = 0; i < 16; i++) {
        ushort4 m = Pr[i * 64 + l];
        float m0 = b2f(m.x), m1 = b2f(m.y), m2 = b2f(m.z), m3 = b2f(m.w);
#pragma unroll
        for (int c = 0; c < S; c++) {
            uint2 hv = *(const uint2*)&hs[c * 2048 + i * 128 + l * 2];
            accv[c] = fmaf(m0, lo2f(hv.x), accv[c]);
            accv[c] = fmaf(m1, hi2f(hv.x), accv[c]);
            accv[c] = fmaf(m2, lo2f(hv.y), accv[c]);
            accv[c] = fmaf(m3, hi2f(hv.y), accv[c]);
        }
    }
#pragma unroll
    for (int c = 0; c < S; c++) {
#pragma unroll
        for (int off = 32; off; off >>= 1) accv[c] += __shfl_xor(accv[c], off, 64);
    }
    if (l == 0) {
#pragma unroll
        for (int c = 0; c < S; c++)
            if (c <= cmax) hout[(size_t)c * NN + r] = accv[c] + bias[(size_t)c * NN + r];
    }
}

// out[n][tt] = h_{tt+17}[n]; hidden_final = h_256
__global__ void emit(const float* __restrict__ houts, float* __restrict__ out) {
    int idx = blockIdx.x * blockDim.x + threadIdx.x;
    if (idx < 240 * NN) {
        int tt = idx >> 12;
        int n  = idx & (NN - 1);
        out[(size_t)n * 240 + tt] = houts[(size_t)(tt + KK + 1) * NN + n];
    } else {
        int n = idx - 240 * NN;
        out[(size_t)240 * NN + n] = houts[(size_t)TT * NN + n];
    }
}

// ---------- launch ----------

extern "C" void kernel_launch(void* const* d_in, const int* in_sizes, int n_in,
                              void* d_out, int out_size, void* d_ws, size_t ws_size,
                              hipStream_t stream) {
    const float* x      = (const float*)d_in[0];
    const float* hidden = (const float*)d_in[1];
    const float* M      = (const float*)d_in[2];
    const float* w      = (const float*)d_in[3];
    const float* xi     = (const float*)d_in[4];

    char* ws = (char*)d_ws;
    float* out = (float*)d_out;
    const size_t MB = 1048576;

    if (ws_size >= 154 * MB) {
        // ---- S = 4 ----
        u16*   Ab     = (u16*)(ws);
        float* tempTf = (float*)(ws + 32 * MB);    // 258 rows
        float* houts  = (float*)(ws + 37 * MB);    // 260 rows
        u16*   c1Tb   = (u16*)(ws + 42 * MB);
        u16*   AbT    = (u16*)(ws + 45 * MB);      // later reused as P2bT
        u16*   P2b    = (u16*)(ws + 77 * MB);
        float* c2Tf   = (float*)(ws + 109 * MB);   // 258 rows
        u16*   P4b    = (u16*)(ws + 114 * MB);
        u16*   c2Tb   = (u16*)(ws + 146 * MB);
        float* c4Tf   = (float*)(ws + 149 * MB);

        zero_tails<<<32, 256, 0, stream>>>(tempTf, c2Tf);
        prep_tempt<<<(TT * NN) / 256, 256, 0, stream>>>(x, w, tempTf);
        convA<<<(NN * NN / 4) / 256, 256, 0, stream>>>(M, xi, Ab);
        convAT<<<dim3(64, 64), 256, 0, stream>>>(M, xi, AbT);
        conv_c1Tb<<<(TT * NN / 4) / 256, 256, 0, stream>>>(tempTf, c1Tb);
        init_h0<<<16, 256, 0, stream>>>(hidden, houts);

        // P2 = A*A
        gemm_bt<<<dim3(32, 32), 256, 0, stream>>>(Ab, AbT, NN, P2b, nullptr, nullptr, 0, NN);
        // c2T = c1T*A^T + shift(+1): both f32 and bf16
        gemm_bt<<<dim3(32, 2), 256, 0, stream>>>(c1Tb, Ab, NN, c2Tb, c2Tf, tempTf, 1, NN);
        // P2bT = transpose(P2b)  (into AbT slot)
        trans_bf<<<dim3(64, 64), 256, 0, stream>>>(P2b, AbT);
        // P4 = P2*P2
        gemm_bt<<<dim3(32, 32), 256, 0, stream>>>(P2b, AbT, NN, P4b, nullptr, nullptr, 0, NN);
        // c4T = c2T*P2^T + shift(+2): f32
        gemm_bt<<<dim3(32, 2), 256, 0, stream>>>(c2Tb, P2b, NN, nullptr, c4Tf, c2Tf, 2, NN);

        // seeds h1..h3
        for (int t = 1; t <= 3; t++)
            step1<<<NN / 8, 512, 0, stream>>>(Ab, tempTf + (size_t)(t - 1) * NN,
                                              houts + (size_t)(t - 1) * NN,
                                              houts + (size_t)t * NN);
        // main: 64 macro steps of 4 chains
        for (int m = 0; m < 64; m++) {
            int t0 = 4 * m;
            macro_step<4><<<NN / 8, 512, 0, stream>>>(
                P4b, c4Tf + (size_t)t0 * NN, houts + (size_t)t0 * NN,
                houts + (size_t)(t0 + 4) * NN, TT - t0 - 4);
        }
        emit<<<(240 * NN + NN) / 256, 256, 0, stream>>>(houts, out);
    } else if (ws_size >= 114 * MB) {
        // ---- S = 2 ----
        u16*   Ab     = (u16*)(ws);
        float* tempTf = (float*)(ws + 32 * MB);
        float* houts  = (float*)(ws + 37 * MB);
        u16*   c1Tb   = (u16*)(ws + 42 * MB);
        u16*   AbT    = (u16*)(ws + 45 * MB);
        u16*   P2b    = (u16*)(ws + 77 * MB);
        float* c2Tf   = (float*)(ws + 109 * MB);

        zero_tails<<<32, 256, 0, stream>>>(tempTf, c2Tf);
        prep_tempt<<<(TT * NN) / 256, 256, 0, stream>>>(x, w, tempTf);
        convA<<<(NN * NN / 4) / 256, 256, 0, stream>>>(M, xi, Ab);
        convAT<<<dim3(64, 64), 256, 0, stream>>>(M, xi, AbT);
        conv_c1Tb<<<(TT * NN / 4) / 256, 256, 0, stream>>>(tempTf, c1Tb);
        init_h0<<<16, 256, 0, stream>>>(hidden, houts);

        gemm_bt<<<dim3(32, 32), 256, 0, stream>>>(Ab, AbT, NN, P2b, nullptr, nullptr, 0, NN);
        gemm_bt<<<dim3(32, 2), 256, 0, stream>>>(c1Tb, Ab, NN, nullptr, c2Tf, tempTf, 1, NN);

        step1<<<NN / 8, 512, 0, stream>>>(Ab, tempTf, houts, houts + NN);
        for (int m = 0; m < 128; m++) {
            int t0 = 2 * m;
            macro_step<2><<<NN / 8, 512, 0, stream>>>(
                P2b, c2Tf + (size_t)t0 * NN, houts + (size_t)t0 * NN,
                houts + (size_t)(t0 + 2) * NN, TT - t0 - 2);
        }
        emit<<<(240 * NN + NN) / 256, 256, 0, stream>>>(houts, out);
    } else {
        // ---- fallback: proven round-1 structure (exact footprint 41,959,424 B) ----
        u16*   Ab     = (u16*)(ws);
        float* tempTf = (float*)(ws + 33554432);   // 256 rows
        float* houts  = (float*)(ws + 37748736);   // 257 rows

        prep_tempt<<<(TT * NN) / 256, 256, 0, stream>>>(x, w, tempTf);
        convA<<<(NN * NN / 4) / 256, 256, 0, stream>>>(M, xi, Ab);
        init_h0<<<16, 256, 0, stream>>>(hidden, houts);
        for (int t = 1; t <= TT; t++)
            step1<<<NN / 8, 512, 0, stream>>>(Ab, tempTf + (size_t)(t - 1) * NN,
                                              houts + (size_t)(t - 1) * NN,
                                              houts + (size_t)t * NN);
        emit<<<(240 * NN + NN) / 256, 256, 0, stream>>>(houts, out);
    }
}

// Round 5
// 1266.813 us; speedup vs baseline: 16.5036x; 1.0101x over previous
//
#include <hip/hip_runtime.h>
#include <stdint.h>

#define NN 4096
#define TT 256
#define KK 16

typedef unsigned short u16;
typedef unsigned int u32;
typedef short bf16x8 __attribute__((ext_vector_type(8)));
typedef float f32x4 __attribute__((ext_vector_type(4)));

__device__ __forceinline__ u32 f2bf(float f) {
    u32 u = __float_as_uint(f);
    return (u + 0x7fffu + ((u >> 16) & 1u)) >> 16; // RNE
}
__device__ __forceinline__ float b2f(u32 v) { return __uint_as_float(v << 16); }
__device__ __forceinline__ float lo2f(u32 u) { return __uint_as_float(u << 16); }
__device__ __forceinline__ float hi2f(u32 u) { return __uint_as_float(u & 0xFFFF0000u); }

__device__ __forceinline__ void gload16(const void* g, void* l) {
    __builtin_amdgcn_global_load_lds(
        (const __attribute__((address_space(1))) void*)g,
        (__attribute__((address_space(3))) void*)l, 16, 0, 0);
}

// ---------- prep ----------

// tempT[t][n] = sum_s x[n][t][s] * w[s]
__global__ void prep_tempt(const float* __restrict__ x, const float* __restrict__ w,
                           float* __restrict__ tempT) {
    int idx = blockIdx.x * blockDim.x + threadIdx.x;
    int t = idx >> 12;
    int n = idx & (NN - 1);
    const float4* xp = (const float4*)(x + ((size_t)n * TT + t) * 8);
    float4 a = xp[0], b = xp[1];
    tempT[idx] = a.x * w[0] + a.y * w[1] + a.z * w[2] + a.w * w[3]
               + b.x * w[4] + b.y * w[5] + b.z * w[6] + b.w * w[7];
}

// Ab = bf16(exp(xi)*M)   (kept for S=2 / fallback paths)
__global__ void convA(const float* __restrict__ M, const float* __restrict__ xi,
                      u16* __restrict__ Ab) {
    int idx = blockIdx.x * blockDim.x + threadIdx.x;   // < NN*NN/4
    float s = expf(xi[0]);
    float4 v = ((const float4*)M)[idx];
    ushort4 o;
    o.x = (u16)f2bf(v.x * s); o.y = (u16)f2bf(v.y * s);
    o.z = (u16)f2bf(v.z * s); o.w = (u16)f2bf(v.w * s);
    ((ushort4*)Ab)[idx] = o;
}

// Fused: Ab = bf16(s*M) (row-major) AND AbT = bf16(s*M)^T — reads M once.
__global__ void convA_AT(const float* __restrict__ M, const float* __restrict__ xi,
                         u16* __restrict__ Ab, u16* __restrict__ AbT) {
    __shared__ float tile[64][65];
    float s = expf(xi[0]);
    int bi = blockIdx.y * 64, bj = blockIdx.x * 64;
    int r = threadIdx.x >> 4, c4 = threadIdx.x & 15;
#pragma unroll
    for (int rr = 0; rr < 64; rr += 16) {
        float4 v = *(const float4*)(M + (size_t)(bi + rr + r) * NN + bj + c4 * 4);
        float v0 = v.x * s, v1 = v.y * s, v2 = v.z * s, v3 = v.w * s;
        ushort4 o;
        o.x = (u16)f2bf(v0); o.y = (u16)f2bf(v1);
        o.z = (u16)f2bf(v2); o.w = (u16)f2bf(v3);
        *(ushort4*)(Ab + (size_t)(bi + rr + r) * NN + bj + c4 * 4) = o;
        tile[rr + r][c4 * 4 + 0] = v0; tile[rr + r][c4 * 4 + 1] = v1;
        tile[rr + r][c4 * 4 + 2] = v2; tile[rr + r][c4 * 4 + 3] = v3;
    }
    __syncthreads();
#pragma unroll
    for (int rr = 0; rr < 64; rr += 16) {
        int j = rr + r;
        ushort4 o;
        o.x = (u16)f2bf(tile[c4 * 4 + 0][j]);
        o.y = (u16)f2bf(tile[c4 * 4 + 1][j]);
        o.z = (u16)f2bf(tile[c4 * 4 + 2][j]);
        o.w = (u16)f2bf(tile[c4 * 4 + 3][j]);
        *(ushort4*)(AbT + (size_t)(bj + j) * NN + bi + c4 * 4) = o;
    }
}

// bf16 transpose (P2b -> P2bT)
__global__ void trans_bf(const u16* __restrict__ src, u16* __restrict__ dst) {
    __shared__ u16 tile[64][72];
    int bi = blockIdx.y * 64, bj = blockIdx.x * 64;
    int r = threadIdx.x >> 4, c4 = threadIdx.x & 15;
#pragma unroll
    for (int rr = 0; rr < 64; rr += 16) {
        ushort4 v = *(const ushort4*)(src + (size_t)(bi + rr + r) * NN + bj + c4 * 4);
        tile[rr + r][c4 * 4 + 0] = v.x; tile[rr + r][c4 * 4 + 1] = v.y;
        tile[rr + r][c4 * 4 + 2] = v.z; tile[rr + r][c4 * 4 + 3] = v.w;
    }
    __syncthreads();
#pragma unroll
    for (int rr = 0; rr < 64; rr += 16) {
        int j = rr + r;
        ushort4 o;
        o.x = tile[c4 * 4 + 0][j]; o.y = tile[c4 * 4 + 1][j];
        o.z = tile[c4 * 4 + 2][j]; o.w = tile[c4 * 4 + 3][j];
        *(ushort4*)(dst + (size_t)(bj + j) * NN + bi + c4 * 4) = o;
    }
}

__global__ void conv_c1Tb(const float* __restrict__ t, u16* __restrict__ o) {
    int idx = blockIdx.x * blockDim.x + threadIdx.x;  // < TT*NN/4
    float4 v = ((const float4*)t)[idx];
    ushort4 r;
    r.x = (u16)f2bf(v.x); r.y = (u16)f2bf(v.y);
    r.z = (u16)f2bf(v.z); r.w = (u16)f2bf(v.w);
    ((ushort4*)o)[idx] = r;
}

__global__ void zero_tails(float* __restrict__ a, float* __restrict__ b,
                           u32* __restrict__ amax) {
    int i = blockIdx.x * blockDim.x + threadIdx.x;    // < 2*NN
    a[(size_t)TT * NN + i] = 0.f;
    b[(size_t)TT * NN + i] = 0.f;
    if (i == 0 && amax) *amax = 0u;
}

__global__ void init_h0(const float* __restrict__ hidden, float* __restrict__ h0) {
    int i = blockIdx.x * blockDim.x + threadIdx.x;
    if (i < NN) h0[i] = hidden[i];
}

// absmax of bf16 array (as f32 bits in *amax)
__global__ void absmax_bf(const u16* __restrict__ p, u32* __restrict__ amax) {
    const uint4* p4 = (const uint4*)p;
    const int n = NN * NN / 8;
    u32 m = 0;
    for (int i = blockIdx.x * blockDim.x + threadIdx.x; i < n;
         i += gridDim.x * blockDim.x) {
        uint4 v = p4[i];
        u32 a;
        a = v.x & 0x7fffu;          m = m > a ? m : a;
        a = (v.x >> 16) & 0x7fffu;  m = m > a ? m : a;
        a = v.y & 0x7fffu;          m = m > a ? m : a;
        a = (v.y >> 16) & 0x7fffu;  m = m > a ? m : a;
        a = v.z & 0x7fffu;          m = m > a ? m : a;
        a = (v.z >> 16) & 0x7fffu;  m = m > a ? m : a;
        a = v.w & 0x7fffu;          m = m > a ? m : a;
        a = (v.w >> 16) & 0x7fffu;  m = m > a ? m : a;
    }
#pragma unroll
    for (int off = 32; off; off >>= 1) {
        u32 o = __shfl_xor(m, off, 64);
        m = m > o ? m : o;
    }
    if ((threadIdx.x & 63) == 0) atomicMax(amax, m << 16);   // f32 bits, monotonic
}

// int8 quantization: q = rint(bf2f(p) * 127/amax)
__global__ void quant_i8(const u16* __restrict__ pb, const u32* __restrict__ amax,
                         signed char* __restrict__ q) {
    int idx = blockIdx.x * blockDim.x + threadIdx.x;      // < NN*NN/4
    float am = __uint_as_float(*amax);
    float s = 127.f / fmaxf(am, 1e-30f);
    ushort4 v = ((const ushort4*)pb)[idx];
    int a0 = (int)rintf(b2f(v.x) * s);
    int a1 = (int)rintf(b2f(v.y) * s);
    int a2 = (int)rintf(b2f(v.z) * s);
    int a3 = (int)rintf(b2f(v.w) * s);
    ((u32*)q)[idx] = (a0 & 0xff) | ((a1 & 0xff) << 8) | ((a2 & 0xff) << 16)
                   | ((u32)(a3 & 0xff) << 24);
}

// ---------- MFMA GEMM (unchanged, round-4 verified) ----------
__global__ __launch_bounds__(256) void gemm_bt(
    const u16* __restrict__ Ag, const u16* __restrict__ Bg, int K,
    u16* __restrict__ outB, float* __restrict__ outF,
    const float* __restrict__ shiftsrc, int shiftr, int N)
{
    __shared__ u16 As[128 * 64];
    __shared__ u16 Bs[128 * 64];
    int tid = threadIdx.x;
    int w = tid >> 6, l = tid & 63;
    int wr = w >> 1, wc = w & 1;
    int bm = blockIdx.y, bn = blockIdx.x;
    const size_t Abase = (size_t)bm * 128 * K;
    const size_t Bbase = (size_t)bn * 128 * K;

    f32x4 zf = {0.f, 0.f, 0.f, 0.f};
    f32x4 acc[4][4];
#pragma unroll
    for (int i = 0; i < 4; i++)
#pragma unroll
        for (int j = 0; j < 4; j++) acc[i][j] = zf;

    for (int kt = 0; kt < K; kt += 64) {
#pragma unroll
        for (int rnd = 0; rnd < 4; rnd++) {
            int i = rnd * 256 + tid;
            int m = i >> 3, cs = i & 7;
            int cg = cs ^ (m & 7);
            gload16(Ag + Abase + (size_t)m * K + kt + cg * 8,
                    (char*)As + (rnd * 256 + w * 64) * 16);
            gload16(Bg + Bbase + (size_t)m * K + kt + cg * 8,
                    (char*)Bs + (rnd * 256 + w * 64) * 16);
        }
        __syncthreads();
#pragma unroll
        for (int kk = 0; kk < 2; kk++) {
            bf16x8 af[4], bfr[4];
#pragma unroll
            for (int mi = 0; mi < 4; mi++) {
                int ml = wr * 64 + mi * 16 + (l & 15);
                int c = (kk * 4 + (l >> 4)) ^ (ml & 7);
                af[mi] = *(const bf16x8*)((const char*)As + ml * 128 + c * 16);
            }
#pragma unroll
            for (int ni = 0; ni < 4; ni++) {
                int nl = wc * 64 + ni * 16 + (l & 15);
                int c = (kk * 4 + (l >> 4)) ^ (nl & 7);
                bfr[ni] = *(const bf16x8*)((const char*)Bs + nl * 128 + c * 16);
            }
#pragma unroll
            for (int mi = 0; mi < 4; mi++)
#pragma unroll
                for (int ni = 0; ni < 4; ni++)
                    acc[mi][ni] = __builtin_amdgcn_mfma_f32_16x16x32_bf16(
                        af[mi], bfr[ni], acc[mi][ni], 0, 0, 0);
        }
        __syncthreads();
    }
#pragma unroll
    for (int mi = 0; mi < 4; mi++)
#pragma unroll
        for (int ni = 0; ni < 4; ni++) {
            f32x4 v = acc[mi][ni];
#pragma unroll
            for (int q = 0; q < 4; q++) {
                int row = bm * 128 + wr * 64 + mi * 16 + (l >> 4) * 4 + q;
                int col = bn * 128 + wc * 64 + ni * 16 + (l & 15);
                float xv = v[q];
                if (shiftsrc) xv += shiftsrc[(size_t)(row + shiftr) * N + col];
                if (outF) outF[(size_t)row * N + col] = xv;
                if (outB) outB[(size_t)row * N + col] = (u16)f2bf(xv);
            }
        }
}

// ---------- recurrence steps ----------

__global__ __launch_bounds__(512) void step1(const u16* __restrict__ Ab,
                                             const float* __restrict__ bcol,
                                             const float* __restrict__ hin,
                                             float* __restrict__ hout) {
    __shared__ float hs[NN];
    int tid = threadIdx.x;
    {
        const float4* hp = (const float4*)hin;
        float4* sp = (float4*)hs;
        sp[tid]       = hp[tid];
        sp[tid + 512] = hp[tid + 512];
    }
    __syncthreads();
    int w = tid >> 6, l = tid & 63;
    int r = blockIdx.x * 8 + w;
    const ushort4* Mr = (const ushort4*)(Ab + (size_t)r * NN);
    const float4*  h4 = (const float4*)hs;
    float acc = 0.f;
#pragma unroll
    for (int i = 0; i < 16; i++) {
        int idx = i * 64 + l;
        ushort4 m = Mr[idx];
        float4  h = h4[idx];
        acc += b2f(m.x) * h.x + b2f(m.y) * h.y + b2f(m.z) * h.z + b2f(m.w) * h.w;
    }
#pragma unroll
    for (int off = 32; off; off >>= 1) acc += __shfl_xor(acc, off, 64);
    if (l == 0) hout[r] = acc + bcol[r];
}

// int8 macro step: 4 chains, f32 h in LDS (XOR-swizzled), hout[c] = dq*(Pq . h[c]) + bias[c]
__global__ __launch_bounds__(512) void macro4_i8(
    const signed char* __restrict__ Pq, const u32* __restrict__ amax,
    const float* __restrict__ bias, const float* __restrict__ hin,
    float* __restrict__ hout, int cmax)
{
    __shared__ float hs[4 * NN];          // 64 KiB -> 2 blocks/CU
    int tid = threadIdx.x;
    {
        const float4* hp = (const float4*)hin;   // 4 contiguous rows
        float4* sp = (float4*)hs;
#pragma unroll
        for (int i = 0; i < 8; i++) {
            int F = i * 512 + tid;
            sp[F ^ ((F >> 3) & 7)] = hp[F];
        }
    }
    __syncthreads();
    int w = tid >> 6, l = tid & 63;
    int r = blockIdx.x * 8 + w;
    float dq = __uint_as_float(*amax) * (1.f / 127.f);
    const uint4* Pr = (const uint4*)(Pq + (size_t)r * NN);
    const float4* h4 = (const float4*)hs;
    float acc[4] = {0.f, 0.f, 0.f, 0.f};
#pragma unroll
    for (int i = 0; i < 4; i++) {
        uint4 qv = Pr[i * 64 + l];
        u32 qq[4] = {qv.x, qv.y, qv.z, qv.w};
        int Fb = i * 256 + l * 4;
#pragma unroll
        for (int c = 0; c < 4; c++) {
            int base = c * 1024 + Fb;
#pragma unroll
            for (int j = 0; j < 4; j++) {
                int F = base + j;
                float4 hv = h4[F ^ ((F >> 3) & 7)];
                u32 q = qq[j];
                acc[c] += (float)(signed char)(q & 0xff)         * hv.x
                        + (float)(signed char)((q >> 8) & 0xff)  * hv.y
                        + (float)(signed char)((q >> 16) & 0xff) * hv.z
                        + (float)(signed char)(q >> 24)          * hv.w;
            }
        }
    }
#pragma unroll
    for (int c = 0; c < 4; c++) {
#pragma unroll
        for (int off = 32; off; off >>= 1) acc[c] += __shfl_xor(acc[c], off, 64);
    }
    if (l == 0) {
#pragma unroll
        for (int c = 0; c < 4; c++)
            if (c <= cmax)
                hout[(size_t)c * NN + r] = acc[c] * dq + bias[(size_t)c * NN + r];
    }
}

// bf16 macro step (S=2 path, round-4 verified)
template <int S>
__global__ __launch_bounds__(512) void macro_step(
    const u16* __restrict__ P, const float* __restrict__ bias,
    const float* __restrict__ hin, float* __restrict__ hout, int cmax)
{
    __shared__ u32 hs[S * 2048];
    int tid = threadIdx.x;
#pragma unroll
    for (int c = 0; c < S; c++) {
        const float4* hp = (const float4*)(hin + c * NN);
        float4 a = hp[tid * 2], b = hp[tid * 2 + 1];
        uint4 o;
        o.x = f2bf(a.x) | (f2bf(a.y) << 16);
        o.y = f2bf(a.z) | (f2bf(a.w) << 16);
        o.z = f2bf(b.x) | (f2bf(b.y) << 16);
        o.w = f2bf(b.z) | (f2bf(b.w) << 16);
        *(uint4*)&hs[c * 2048 + tid * 4] = o;
    }
    __syncthreads();
    int w = tid >> 6, l = tid & 63;
    int r = blockIdx.x * 8 + w;
    const ushort4* Pr = (const ushort4*)(P + (size_t)r * NN);
    float accv[S];
#pragma unroll
    for (int c = 0; c < S; c++) accv[c] = 0.f;
#pragma unroll
    for (int i = 0; i < 16; i++) {
        ushort4 m = Pr[i * 64 + l];
        float m0 = b2f(m.x), m1 = b2f(m.y), m2 = b2f(m.z), m3 = b2f(m.w);
#pragma unroll
        for (int c = 0; c < S; c++) {
            uint2 hv = *(const uint2*)&hs[c * 2048 + i * 128 + l * 2];
            accv[c] = fmaf(m0, lo2f(hv.x), accv[c]);
            accv[c] = fmaf(m1, hi2f(hv.x), accv[c]);
            accv[c] = fmaf(m2, lo2f(hv.y), accv[c]);
            accv[c] = fmaf(m3, hi2f(hv.y), accv[c]);
        }
    }
#pragma unroll
    for (int c = 0; c < S; c++) {
#pragma unroll
        for (int off = 32; off; off >>= 1) accv[c] += __shfl_xor(accv[c], off, 64);
    }
    if (l == 0) {
#pragma unroll
        for (int c = 0; c < S; c++)
            if (c <= cmax) hout[(size_t)c * NN + r] = accv[c] + bias[(size_t)c * NN + r];
    }
}

__global__ void emit(const float* __restrict__ houts, float* __restrict__ out) {
    int idx = blockIdx.x * blockDim.x + threadIdx.x;
    if (idx < 240 * NN) {
        int tt = idx >> 12;
        int n  = idx & (NN - 1);
        out[(size_t)n * 240 + tt] = houts[(size_t)(tt + KK + 1) * NN + n];
    } else {
        int n = idx - 240 * NN;
        out[(size_t)240 * NN + n] = houts[(size_t)TT * NN + n];
    }
}

// ---------- launch ----------

extern "C" void kernel_launch(void* const* d_in, const int* in_sizes, int n_in,
                              void* d_out, int out_size, void* d_ws, size_t ws_size,
                              hipStream_t stream) {
    const float* x      = (const float*)d_in[0];
    const float* hidden = (const float*)d_in[1];
    const float* M      = (const float*)d_in[2];
    const float* w      = (const float*)d_in[3];
    const float* xi     = (const float*)d_in[4];

    char* ws = (char*)d_ws;
    float* out = (float*)d_out;
    const size_t MB = 1048576;

    if (ws_size >= 154 * MB) {
        // ---- S = 4, int8 sweeps ----
        u16*   Ab     = (u16*)(ws);
        float* tempTf = (float*)(ws + 32 * MB);
        float* houts  = (float*)(ws + 37 * MB);
        u16*   c1Tb   = (u16*)(ws + 42 * MB);
        u16*   AbT    = (u16*)(ws + 45 * MB);      // reused as P2bT
        u16*   P2b    = (u16*)(ws + 77 * MB);      // later overlaid by P4q
        float* c2Tf   = (float*)(ws + 109 * MB);
        u16*   P4b    = (u16*)(ws + 114 * MB);
        u16*   c2Tb   = (u16*)(ws + 146 * MB);
        float* c4Tf   = (float*)(ws + 149 * MB);
        signed char* P4q = (signed char*)(ws + 77 * MB);   // 16 MiB, after P2b dead
        u32*   amax   = (u32*)(ws + 153 * MB + 512 * 1024);

        zero_tails<<<32, 256, 0, stream>>>(tempTf, c2Tf, amax);
        prep_tempt<<<(TT * NN) / 256, 256, 0, stream>>>(x, w, tempTf);
        convA_AT<<<dim3(64, 64), 256, 0, stream>>>(M, xi, Ab, AbT);
        conv_c1Tb<<<(TT * NN / 4) / 256, 256, 0, stream>>>(tempTf, c1Tb);
        init_h0<<<16, 256, 0, stream>>>(hidden, houts);

        // P2 = A*A
        gemm_bt<<<dim3(32, 32), 256, 0, stream>>>(Ab, AbT, NN, P2b, nullptr, nullptr, 0, NN);
        // c2T = c1T*A^T + shift(+1)
        gemm_bt<<<dim3(32, 2), 256, 0, stream>>>(c1Tb, Ab, NN, c2Tb, c2Tf, tempTf, 1, NN);
        // P2bT
        trans_bf<<<dim3(64, 64), 256, 0, stream>>>(P2b, AbT);
        // P4 = P2*P2
        gemm_bt<<<dim3(32, 32), 256, 0, stream>>>(P2b, AbT, NN, P4b, nullptr, nullptr, 0, NN);
        // c4T = c2T*P2^T + shift(+2)
        gemm_bt<<<dim3(32, 2), 256, 0, stream>>>(c2Tb, P2b, NN, nullptr, c4Tf, c2Tf, 2, NN);

        // quantize P4 -> int8 (P2b now dead; P4q overlays it)
        absmax_bf<<<1024, 256, 0, stream>>>(P4b, amax);
        quant_i8<<<(NN * NN / 4) / 256, 256, 0, stream>>>(P4b, amax, P4q);

        // seeds h1..h3
        for (int t = 1; t <= 3; t++)
            step1<<<NN / 8, 512, 0, stream>>>(Ab, tempTf + (size_t)(t - 1) * NN,
                                              houts + (size_t)(t - 1) * NN,
                                              houts + (size_t)t * NN);
        // 64 int8 macro steps
        for (int m = 0; m < 64; m++) {
            int t0 = 4 * m;
            macro4_i8<<<NN / 8, 512, 0, stream>>>(
                P4q, amax, c4Tf + (size_t)t0 * NN, houts + (size_t)t0 * NN,
                houts + (size_t)(t0 + 4) * NN, TT - t0 - 4);
        }
        emit<<<(240 * NN + NN) / 256, 256, 0, stream>>>(houts, out);
    } else if (ws_size >= 114 * MB) {
        // ---- S = 2 (round-4 verified) ----
        u16*   Ab     = (u16*)(ws);
        float* tempTf = (float*)(ws + 32 * MB);
        float* houts  = (float*)(ws + 37 * MB);
        u16*   c1Tb   = (u16*)(ws + 42 * MB);
        u16*   AbT    = (u16*)(ws + 45 * MB);
        u16*   P2b    = (u16*)(ws + 77 * MB);
        float* c2Tf   = (float*)(ws + 109 * MB);

        zero_tails<<<32, 256, 0, stream>>>(tempTf, c2Tf, nullptr);
        prep_tempt<<<(TT * NN) / 256, 256, 0, stream>>>(x, w, tempTf);
        convA_AT<<<dim3(64, 64), 256, 0, stream>>>(M, xi, Ab, AbT);
        conv_c1Tb<<<(TT * NN / 4) / 256, 256, 0, stream>>>(tempTf, c1Tb);
        init_h0<<<16, 256, 0, stream>>>(hidden, houts);

        gemm_bt<<<dim3(32, 32), 256, 0, stream>>>(Ab, AbT, NN, P2b, nullptr, nullptr, 0, NN);
        gemm_bt<<<dim3(32, 2), 256, 0, stream>>>(c1Tb, Ab, NN, nullptr, c2Tf, tempTf, 1, NN);

        step1<<<NN / 8, 512, 0, stream>>>(Ab, tempTf, houts, houts + NN);
        for (int m = 0; m < 128; m++) {
            int t0 = 2 * m;
            macro_step<2><<<NN / 8, 512, 0, stream>>>(
                P2b, c2Tf + (size_t)t0 * NN, houts + (size_t)t0 * NN,
                houts + (size_t)(t0 + 2) * NN, TT - t0 - 2);
        }
        emit<<<(240 * NN + NN) / 256, 256, 0, stream>>>(houts, out);
    } else {
        // ---- fallback: round-1 structure ----
        u16*   Ab     = (u16*)(ws);
        float* tempTf = (float*)(ws + 33554432);
        float* houts  = (float*)(ws + 37748736);

        prep_tempt<<<(TT * NN) / 256, 256, 0, stream>>>(x, w, tempTf);
        convA<<<(NN * NN / 4) / 256, 256, 0, stream>>>(M, xi, Ab);
        init_h0<<<16, 256, 0, stream>>>(hidden, houts);
        for (int t = 1; t <= TT; t++)
            step1<<<NN / 8, 512, 0, stream>>>(Ab, tempTf + (size_t)(t - 1) * NN,
                                              houts + (size_t)(t - 1) * NN,
                                              houts + (size_t)t * NN);
        emit<<<(240 * NN + NN) / 256, 256, 0, stream>>>(houts, out);
    }
}

// Round 6
// 977.639 us; speedup vs baseline: 21.3851x; 1.2958x over previous
//
#include <hip/hip_runtime.h>
#include <hip/hip_fp8.h>
#include <stdint.h>

#define NN 4096
#define TT 256
#define KK 16

typedef unsigned short u16;
typedef unsigned int u32;
typedef unsigned char u8;
typedef short bf16x8 __attribute__((ext_vector_type(8)));
typedef float f32x4 __attribute__((ext_vector_type(4)));

__device__ __forceinline__ u32 f2bf(float f) {
    u32 u = __float_as_uint(f);
    return (u + 0x7fffu + ((u >> 16) & 1u)) >> 16; // RNE
}
__device__ __forceinline__ float b2f(u32 v) { return __uint_as_float(v << 16); }
__device__ __forceinline__ float lo2f(u32 u) { return __uint_as_float(u << 16); }
__device__ __forceinline__ float hi2f(u32 u) { return __uint_as_float(u & 0xFFFF0000u); }
__device__ __forceinline__ u8 f2fp8(float f) { __hip_fp8_e4m3 q(f); return (u8)q.__x; }

__device__ __forceinline__ void gload16(const void* g, void* l) {
    __builtin_amdgcn_global_load_lds(
        (const __attribute__((address_space(1))) void*)g,
        (__attribute__((address_space(3))) void*)l, 16, 0, 0);
}

// ---------- prep ----------

// tempT[t][n] = sum_s x[n][t][s] * w[s]
__global__ void prep_tempt(const float* __restrict__ x, const float* __restrict__ w,
                           float* __restrict__ tempT) {
    int idx = blockIdx.x * blockDim.x + threadIdx.x;
    int t = idx >> 12;
    int n = idx & (NN - 1);
    const float4* xp = (const float4*)(x + ((size_t)n * TT + t) * 8);
    float4 a = xp[0], b = xp[1];
    tempT[idx] = a.x * w[0] + a.y * w[1] + a.z * w[2] + a.w * w[3]
               + b.x * w[4] + b.y * w[5] + b.z * w[6] + b.w * w[7];
}

// Ab = bf16(exp(xi)*M)  (fallback path)
__global__ void convA(const float* __restrict__ M, const float* __restrict__ xi,
                      u16* __restrict__ Ab) {
    int idx = blockIdx.x * blockDim.x + threadIdx.x;   // < NN*NN/4
    float s = expf(xi[0]);
    float4 v = ((const float4*)M)[idx];
    ushort4 o;
    o.x = (u16)f2bf(v.x * s); o.y = (u16)f2bf(v.y * s);
    o.z = (u16)f2bf(v.z * s); o.w = (u16)f2bf(v.w * s);
    ((ushort4*)Ab)[idx] = o;
}

// Fused: Ab = bf16(s*M) AND AbT = bf16(s*M)^T — reads M once.
__global__ void convA_AT(const float* __restrict__ M, const float* __restrict__ xi,
                         u16* __restrict__ Ab, u16* __restrict__ AbT) {
    __shared__ float tile[64][65];
    float s = expf(xi[0]);
    int bi = blockIdx.y * 64, bj = blockIdx.x * 64;
    int r = threadIdx.x >> 4, c4 = threadIdx.x & 15;
#pragma unroll
    for (int rr = 0; rr < 64; rr += 16) {
        float4 v = *(const float4*)(M + (size_t)(bi + rr + r) * NN + bj + c4 * 4);
        float v0 = v.x * s, v1 = v.y * s, v2 = v.z * s, v3 = v.w * s;
        ushort4 o;
        o.x = (u16)f2bf(v0); o.y = (u16)f2bf(v1);
        o.z = (u16)f2bf(v2); o.w = (u16)f2bf(v3);
        *(ushort4*)(Ab + (size_t)(bi + rr + r) * NN + bj + c4 * 4) = o;
        tile[rr + r][c4 * 4 + 0] = v0; tile[rr + r][c4 * 4 + 1] = v1;
        tile[rr + r][c4 * 4 + 2] = v2; tile[rr + r][c4 * 4 + 3] = v3;
    }
    __syncthreads();
#pragma unroll
    for (int rr = 0; rr < 64; rr += 16) {
        int j = rr + r;
        ushort4 o;
        o.x = (u16)f2bf(tile[c4 * 4 + 0][j]);
        o.y = (u16)f2bf(tile[c4 * 4 + 1][j]);
        o.z = (u16)f2bf(tile[c4 * 4 + 2][j]);
        o.w = (u16)f2bf(tile[c4 * 4 + 3][j]);
        *(ushort4*)(AbT + (size_t)(bj + j) * NN + bi + c4 * 4) = o;
    }
}

// bf16 transpose (P2b -> P2bT)
__global__ void trans_bf(const u16* __restrict__ src, u16* __restrict__ dst) {
    __shared__ u16 tile[64][72];
    int bi = blockIdx.y * 64, bj = blockIdx.x * 64;
    int r = threadIdx.x >> 4, c4 = threadIdx.x & 15;
#pragma unroll
    for (int rr = 0; rr < 64; rr += 16) {
        ushort4 v = *(const ushort4*)(src + (size_t)(bi + rr + r) * NN + bj + c4 * 4);
        tile[rr + r][c4 * 4 + 0] = v.x; tile[rr + r][c4 * 4 + 1] = v.y;
        tile[rr + r][c4 * 4 + 2] = v.z; tile[rr + r][c4 * 4 + 3] = v.w;
    }
    __syncthreads();
#pragma unroll
    for (int rr = 0; rr < 64; rr += 16) {
        int j = rr + r;
        ushort4 o;
        o.x = tile[c4 * 4 + 0][j]; o.y = tile[c4 * 4 + 1][j];
        o.z = tile[c4 * 4 + 2][j]; o.w = tile[c4 * 4 + 3][j];
        *(ushort4*)(dst + (size_t)(bj + j) * NN + bi + c4 * 4) = o;
    }
}

__global__ void conv_c1Tb(const float* __restrict__ t, u16* __restrict__ o) {
    int idx = blockIdx.x * blockDim.x + threadIdx.x;  // < TT*NN/4
    float4 v = ((const float4*)t)[idx];
    ushort4 r;
    r.x = (u16)f2bf(v.x); r.y = (u16)f2bf(v.y);
    r.z = (u16)f2bf(v.z); r.w = (u16)f2bf(v.w);
    ((ushort4*)o)[idx] = r;
}

__global__ void zero_tails(float* __restrict__ a, float* __restrict__ b,
                           u32* __restrict__ amax) {
    int i = blockIdx.x * blockDim.x + threadIdx.x;    // < 2*NN
    a[(size_t)TT * NN + i] = 0.f;
    b[(size_t)TT * NN + i] = 0.f;
    if (i == 0 && amax) *amax = 0u;
}

__global__ void init_h0(const float* __restrict__ hidden, float* __restrict__ h0) {
    int i = blockIdx.x * blockDim.x + threadIdx.x;
    if (i < NN) h0[i] = hidden[i];
}

// absmax of bf16 array (as f32 bits in *amax)
__global__ void absmax_bf(const u16* __restrict__ p, u32* __restrict__ amax) {
    const uint4* p4 = (const uint4*)p;
    const int n = NN * NN / 8;
    u32 m = 0;
    for (int i = blockIdx.x * blockDim.x + threadIdx.x; i < n;
         i += gridDim.x * blockDim.x) {
        uint4 v = p4[i];
        u32 a;
        a = v.x & 0x7fffu;          m = m > a ? m : a;
        a = (v.x >> 16) & 0x7fffu;  m = m > a ? m : a;
        a = v.y & 0x7fffu;          m = m > a ? m : a;
        a = (v.y >> 16) & 0x7fffu;  m = m > a ? m : a;
        a = v.z & 0x7fffu;          m = m > a ? m : a;
        a = (v.z >> 16) & 0x7fffu;  m = m > a ? m : a;
        a = v.w & 0x7fffu;          m = m > a ? m : a;
        a = (v.w >> 16) & 0x7fffu;  m = m > a ? m : a;
    }
#pragma unroll
    for (int off = 32; off; off >>= 1) {
        u32 o = __shfl_xor(m, off, 64);
        m = m > o ? m : o;
    }
    if ((threadIdx.x & 63) == 0) atomicMax(amax, m << 16);   // f32 bits, monotonic
}

// fp8 quantization of P4 (scale = 2^floor(log2(448/amax))), emitted in
// MFMA-A-fragment-permuted order: dst uint2 index d = ((b*8+w)*16+i)*64+l,
// holding P'[row=b*16+(l&15)][k = w*512+i*32+(l>>4)*8 .. +7].
__global__ void quant_fp8_perm(const u16* __restrict__ P4b,
                               const u32* __restrict__ amax,
                               uint2* __restrict__ qP) {
    int d = blockIdx.x * blockDim.x + threadIdx.x;   // < 2^21
    int l = d & 63, i = (d >> 6) & 15, w = (d >> 10) & 7, b = d >> 13;
    float am = __uint_as_float(*amax);
    float s = exp2f(floorf(log2f(448.f / fmaxf(am, 1e-30f))));
    int row = b * 16 + (l & 15);
    int k = w * 512 + i * 32 + (l >> 4) * 8;
    const ushort4* src = (const ushort4*)(P4b + (size_t)row * NN + k);
    ushort4 v0 = src[0], v1 = src[1];
    u32 lo = (u32)f2fp8(b2f(v0.x) * s)
           | ((u32)f2fp8(b2f(v0.y) * s) << 8)
           | ((u32)f2fp8(b2f(v0.z) * s) << 16)
           | ((u32)f2fp8(b2f(v0.w) * s) << 24);
    u32 hi = (u32)f2fp8(b2f(v1.x) * s)
           | ((u32)f2fp8(b2f(v1.y) * s) << 8)
           | ((u32)f2fp8(b2f(v1.z) * s) << 16)
           | ((u32)f2fp8(b2f(v1.w) * s) << 24);
    uint2 o; o.x = lo; o.y = hi;
    qP[d] = o;
}

// hb8[0][c][n] = fp8(h_c[n]) for c=0..3 (seed chains)
__global__ void build_hb0(const float* __restrict__ houts, u8* __restrict__ hb0) {
    int i = blockIdx.x * blockDim.x + threadIdx.x;   // < 4*NN
    int c = i >> 12, n = i & (NN - 1);
    hb0[i] = f2fp8(houts[(size_t)c * NN + n]);
}

// ---------- MFMA GEMM (round-4/5 verified) ----------
__global__ __launch_bounds__(256) void gemm_bt(
    const u16* __restrict__ Ag, const u16* __restrict__ Bg, int K,
    u16* __restrict__ outB, float* __restrict__ outF,
    const float* __restrict__ shiftsrc, int shiftr, int N)
{
    __shared__ u16 As[128 * 64];
    __shared__ u16 Bs[128 * 64];
    int tid = threadIdx.x;
    int w = tid >> 6, l = tid & 63;
    int wr = w >> 1, wc = w & 1;
    int bm = blockIdx.y, bn = blockIdx.x;
    const size_t Abase = (size_t)bm * 128 * K;
    const size_t Bbase = (size_t)bn * 128 * K;

    f32x4 zf = {0.f, 0.f, 0.f, 0.f};
    f32x4 acc[4][4];
#pragma unroll
    for (int i = 0; i < 4; i++)
#pragma unroll
        for (int j = 0; j < 4; j++) acc[i][j] = zf;

    for (int kt = 0; kt < K; kt += 64) {
#pragma unroll
        for (int rnd = 0; rnd < 4; rnd++) {
            int i = rnd * 256 + tid;
            int m = i >> 3, cs = i & 7;
            int cg = cs ^ (m & 7);
            gload16(Ag + Abase + (size_t)m * K + kt + cg * 8,
                    (char*)As + (rnd * 256 + w * 64) * 16);
            gload16(Bg + Bbase + (size_t)m * K + kt + cg * 8,
                    (char*)Bs + (rnd * 256 + w * 64) * 16);
        }
        __syncthreads();
#pragma unroll
        for (int kk = 0; kk < 2; kk++) {
            bf16x8 af[4], bfr[4];
#pragma unroll
            for (int mi = 0; mi < 4; mi++) {
                int ml = wr * 64 + mi * 16 + (l & 15);
                int c = (kk * 4 + (l >> 4)) ^ (ml & 7);
                af[mi] = *(const bf16x8*)((const char*)As + ml * 128 + c * 16);
            }
#pragma unroll
            for (int ni = 0; ni < 4; ni++) {
                int nl = wc * 64 + ni * 16 + (l & 15);
                int c = (kk * 4 + (l >> 4)) ^ (nl & 7);
                bfr[ni] = *(const bf16x8*)((const char*)Bs + nl * 128 + c * 16);
            }
#pragma unroll
            for (int mi = 0; mi < 4; mi++)
#pragma unroll
                for (int ni = 0; ni < 4; ni++)
                    acc[mi][ni] = __builtin_amdgcn_mfma_f32_16x16x32_bf16(
                        af[mi], bfr[ni], acc[mi][ni], 0, 0, 0);
        }
        __syncthreads();
    }
#pragma unroll
    for (int mi = 0; mi < 4; mi++)
#pragma unroll
        for (int ni = 0; ni < 4; ni++) {
            f32x4 v = acc[mi][ni];
#pragma unroll
            for (int q = 0; q < 4; q++) {
                int row = bm * 128 + wr * 64 + mi * 16 + (l >> 4) * 4 + q;
                int col = bn * 128 + wc * 64 + ni * 16 + (l & 15);
                float xv = v[q];
                if (shiftsrc) xv += shiftsrc[(size_t)(row + shiftr) * N + col];
                if (outF) outF[(size_t)row * N + col] = xv;
                if (outB) outB[(size_t)row * N + col] = (u16)f2bf(xv);
            }
        }
}

// ---------- recurrence ----------

__global__ __launch_bounds__(512) void step1(const u16* __restrict__ Ab,
                                             const float* __restrict__ bcol,
                                             const float* __restrict__ hin,
                                             float* __restrict__ hout) {
    __shared__ float hs[NN];
    int tid = threadIdx.x;
    {
        const float4* hp = (const float4*)hin;
        float4* sp = (float4*)hs;
        sp[tid]       = hp[tid];
        sp[tid + 512] = hp[tid + 512];
    }
    __syncthreads();
    int w = tid >> 6, l = tid & 63;
    int r = blockIdx.x * 8 + w;
    const ushort4* Mr = (const ushort4*)(Ab + (size_t)r * NN);
    const float4*  h4 = (const float4*)hs;
    float acc = 0.f;
#pragma unroll
    for (int i = 0; i < 16; i++) {
        int idx = i * 64 + l;
        ushort4 m = Mr[idx];
        float4  h = h4[idx];
        acc += b2f(m.x) * h.x + b2f(m.y) * h.y + b2f(m.z) * h.z + b2f(m.w) * h.w;
    }
#pragma unroll
    for (int off = 32; off; off >>= 1) acc += __shfl_xor(acc, off, 64);
    if (l == 0) hout[r] = acc + bcol[r];
}

// MFMA-fp8 macro step: 256 blocks x 8 waves; block owns 16 rows, wave owns a
// K=512 slice; chains = cols 0..3 of the 16x16 C tile; cross-wave LDS reduce.
// hout[c][r] = inv_s * (P4' . h8[c])[r] + bias[c][r]
__global__ __launch_bounds__(512) void sweep_fp8(
    const uint2* __restrict__ qP, const u32* __restrict__ amax,
    const float* __restrict__ bias, const u8* __restrict__ hin8,
    float* __restrict__ hout, u8* __restrict__ hout8, int cmax)
{
    __shared__ u8 hs[4][NN];          // 16 KiB fp8 h chains
    __shared__ float part[8][16][16]; // 8 KiB partial C tiles
    int tid = threadIdx.x, b = blockIdx.x;
    int w = tid >> 6, l = tid & 63;

    ((uint4*)&hs[0][0])[tid]       = ((const uint4*)hin8)[tid];
    ((uint4*)&hs[0][0])[tid + 512] = ((const uint4*)hin8)[tid + 512];
    __syncthreads();

    int c = l & 15, g = l >> 4;
    const u8* hrow = &hs[c & 3][w * 512 + g * 8];
    const uint2* ap = qP + ((size_t)(b * 8 + w) * 16) * 64 + l;

    f32x4 acc = {0.f, 0.f, 0.f, 0.f};
#pragma unroll
    for (int i = 0; i < 16; i++) {
        uint2 av = ap[i * 64];
        long long a8 = ((long long)av.y << 32) | (u32)av.x;
        uint2 hv = *(const uint2*)(hrow + i * 32);
        long long b8 = (c < 4) ? (((long long)hv.y << 32) | (u32)hv.x) : 0LL;
        acc = __builtin_amdgcn_mfma_f32_16x16x32_fp8_fp8(a8, b8, acc, 0, 0, 0);
    }
    // C/D layout (m89-verified, dtype-independent): col=l&15, row=g*4+q
#pragma unroll
    for (int q = 0; q < 4; q++) part[w][g * 4 + q][c] = acc[q];
    __syncthreads();

    if (tid < 256) {
        int r = tid >> 4, cc = tid & 15;
        if (cc < 4) {
            float s = 0.f;
#pragma unroll
            for (int ww = 0; ww < 8; ww++) s += part[ww][r][cc];
            float am = __uint_as_float(*amax);
            float inv = exp2f(-floorf(log2f(448.f / fmaxf(am, 1e-30f))));
            int row = b * 16 + r;
            float y = s * inv + bias[(size_t)cc * NN + row];
            if (cc <= cmax) hout[(size_t)cc * NN + row] = y;
            hout8[(size_t)cc * NN + row] = f2fp8(y);
        }
    }
}

// bf16 macro step (S=2 path, round-4 verified)
template <int S>
__global__ __launch_bounds__(512) void macro_step(
    const u16* __restrict__ P, const float* __restrict__ bias,
    const float* __restrict__ hin, float* __restrict__ hout, int cmax)
{
    __shared__ u32 hs[S * 2048];
    int tid = threadIdx.x;
#pragma unroll
    for (int c = 0; c < S; c++) {
        const float4* hp = (const float4*)(hin + c * NN);
        float4 a = hp[tid * 2], b = hp[tid * 2 + 1];
        uint4 o;
        o.x = f2bf(a.x) | (f2bf(a.y) << 16);
        o.y = f2bf(a.z) | (f2bf(a.w) << 16);
        o.z = f2bf(b.x) | (f2bf(b.y) << 16);
        o.w = f2bf(b.z) | (f2bf(b.w) << 16);
        *(uint4*)&hs[c * 2048 + tid * 4] = o;
    }
    __syncthreads();
    int w = tid >> 6, l = tid & 63;
    int r = blockIdx.x * 8 + w;
    const ushort4* Pr = (const ushort4*)(P + (size_t)r * NN);
    float accv[S];
#pragma unroll
    for (int c = 0; c < S; c++) accv[c] = 0.f;
#pragma unroll
    for (int i = 0; i < 16; i++) {
        ushort4 m = Pr[i * 64 + l];
        float m0 = b2f(m.x), m1 = b2f(m.y), m2 = b2f(m.z), m3 = b2f(m.w);
#pragma unroll
        for (int c = 0; c < S; c++) {
            uint2 hv = *(const uint2*)&hs[c * 2048 + i * 128 + l * 2];
            accv[c] = fmaf(m0, lo2f(hv.x), accv[c]);
            accv[c] = fmaf(m1, hi2f(hv.x), accv[c]);
            accv[c] = fmaf(m2, lo2f(hv.y), accv[c]);
            accv[c] = fmaf(m3, hi2f(hv.y), accv[c]);
        }
    }
#pragma unroll
    for (int c = 0; c < S; c++) {
#pragma unroll
        for (int off = 32; off; off >>= 1) accv[c] += __shfl_xor(accv[c], off, 64);
    }
    if (l == 0) {
#pragma unroll
        for (int c = 0; c < S; c++)
            if (c <= cmax) hout[(size_t)c * NN + r] = accv[c] + bias[(size_t)c * NN + r];
    }
}

__global__ void emit(const float* __restrict__ houts, float* __restrict__ out) {
    int idx = blockIdx.x * blockDim.x + threadIdx.x;
    if (idx < 240 * NN) {
        int tt = idx >> 12;
        int n  = idx & (NN - 1);
        out[(size_t)n * 240 + tt] = houts[(size_t)(tt + KK + 1) * NN + n];
    } else {
        int n = idx - 240 * NN;
        out[(size_t)240 * NN + n] = houts[(size_t)TT * NN + n];
    }
}

// ---------- launch ----------

extern "C" void kernel_launch(void* const* d_in, const int* in_sizes, int n_in,
                              void* d_out, int out_size, void* d_ws, size_t ws_size,
                              hipStream_t stream) {
    const float* x      = (const float*)d_in[0];
    const float* hidden = (const float*)d_in[1];
    const float* M      = (const float*)d_in[2];
    const float* w      = (const float*)d_in[3];
    const float* xi     = (const float*)d_in[4];

    char* ws = (char*)d_ws;
    float* out = (float*)d_out;
    const size_t MB = 1048576;

    if (ws_size >= 154 * MB) {
        // ---- S = 4, MFMA-fp8 sweeps ----
        u16*   Ab     = (u16*)(ws);
        float* tempTf = (float*)(ws + 32 * MB);
        float* houts  = (float*)(ws + 37 * MB);
        u16*   c1Tb   = (u16*)(ws + 42 * MB);
        u16*   AbT    = (u16*)(ws + 45 * MB);       // reused as P2bT
        u16*   P2b    = (u16*)(ws + 77 * MB);       // dead after P4 -> qP overlays
        float* c2Tf   = (float*)(ws + 109 * MB);
        u16*   P4b    = (u16*)(ws + 114 * MB);
        u16*   c2Tb   = (u16*)(ws + 146 * MB);
        float* c4Tf   = (float*)(ws + 149 * MB);
        uint2* qP     = (uint2*)(ws + 77 * MB);     // 16 MiB fp8 permuted P4'
        u8*    hb8    = (u8*)(ws + 93 * MB);        // 65 x [4][4096] fp8
        u32*   amax   = (u32*)(ws + 153 * MB + 512 * 1024);

        zero_tails<<<32, 256, 0, stream>>>(tempTf, c2Tf, amax);
        prep_tempt<<<(TT * NN) / 256, 256, 0, stream>>>(x, w, tempTf);
        convA_AT<<<dim3(64, 64), 256, 0, stream>>>(M, xi, Ab, AbT);
        conv_c1Tb<<<(TT * NN / 4) / 256, 256, 0, stream>>>(tempTf, c1Tb);
        init_h0<<<16, 256, 0, stream>>>(hidden, houts);

        // P2 = A*A
        gemm_bt<<<dim3(32, 32), 256, 0, stream>>>(Ab, AbT, NN, P2b, nullptr, nullptr, 0, NN);
        // c2T = c1T*A^T + shift(+1)
        gemm_bt<<<dim3(32, 2), 256, 0, stream>>>(c1Tb, Ab, NN, c2Tb, c2Tf, tempTf, 1, NN);
        // P2bT
        trans_bf<<<dim3(64, 64), 256, 0, stream>>>(P2b, AbT);
        // P4 = P2*P2
        gemm_bt<<<dim3(32, 32), 256, 0, stream>>>(P2b, AbT, NN, P4b, nullptr, nullptr, 0, NN);
        // c4T = c2T*P2^T + shift(+2)
        gemm_bt<<<dim3(32, 2), 256, 0, stream>>>(c2Tb, P2b, NN, nullptr, c4Tf, c2Tf, 2, NN);

        // quantize P4 -> fp8 (power-of-2 scale), MFMA-permuted layout
        absmax_bf<<<1024, 256, 0, stream>>>(P4b, amax);
        quant_fp8_perm<<<(1 << 21) / 256, 256, 0, stream>>>(P4b, amax, qP);

        // seeds h1..h3
        for (int t = 1; t <= 3; t++)
            step1<<<NN / 8, 512, 0, stream>>>(Ab, tempTf + (size_t)(t - 1) * NN,
                                              houts + (size_t)(t - 1) * NN,
                                              houts + (size_t)t * NN);
        build_hb0<<<(4 * NN) / 256, 256, 0, stream>>>(houts, hb8);

        // 64 MFMA macro steps
        for (int m = 0; m < 64; m++) {
            int t0 = 4 * m;
            sweep_fp8<<<256, 512, 0, stream>>>(
                qP, amax, c4Tf + (size_t)t0 * NN,
                hb8 + (size_t)m * 4 * NN,
                houts + (size_t)(t0 + 4) * NN,
                hb8 + (size_t)(m + 1) * 4 * NN,
                TT - t0 - 4);
        }
        emit<<<(240 * NN + NN) / 256, 256, 0, stream>>>(houts, out);
    } else if (ws_size >= 114 * MB) {
        // ---- S = 2 (round-4 verified) ----
        u16*   Ab     = (u16*)(ws);
        float* tempTf = (float*)(ws + 32 * MB);
        float* houts  = (float*)(ws + 37 * MB);
        u16*   c1Tb   = (u16*)(ws + 42 * MB);
        u16*   AbT    = (u16*)(ws + 45 * MB);
        u16*   P2b    = (u16*)(ws + 77 * MB);
        float* c2Tf   = (float*)(ws + 109 * MB);

        zero_tails<<<32, 256, 0, stream>>>(tempTf, c2Tf, nullptr);
        prep_tempt<<<(TT * NN) / 256, 256, 0, stream>>>(x, w, tempTf);
        convA_AT<<<dim3(64, 64), 256, 0, stream>>>(M, xi, Ab, AbT);
        conv_c1Tb<<<(TT * NN / 4) / 256, 256, 0, stream>>>(tempTf, c1Tb);
        init_h0<<<16, 256, 0, stream>>>(hidden, houts);

        gemm_bt<<<dim3(32, 32), 256, 0, stream>>>(Ab, AbT, NN, P2b, nullptr, nullptr, 0, NN);
        gemm_bt<<<dim3(32, 2), 256, 0, stream>>>(c1Tb, Ab, NN, nullptr, c2Tf, tempTf, 1, NN);

        step1<<<NN / 8, 512, 0, stream>>>(Ab, tempTf, houts, houts + NN);
        for (int m = 0; m < 128; m++) {
            int t0 = 2 * m;
            macro_step<2><<<NN / 8, 512, 0, stream>>>(
                P2b, c2Tf + (size_t)t0 * NN, houts + (size_t)t0 * NN,
                houts + (size_t)(t0 + 2) * NN, TT - t0 - 2);
        }
        emit<<<(240 * NN + NN) / 256, 256, 0, stream>>>(houts, out);
    } else {
        // ---- fallback: round-1 structure ----
        u16*   Ab     = (u16*)(ws);
        float* tempTf = (float*)(ws + 33554432);
        float* houts  = (float*)(ws + 37748736);

        prep_tempt<<<(TT * NN) / 256, 256, 0, stream>>>(x, w, tempTf);
        convA<<<(NN * NN / 4) / 256, 256, 0, stream>>>(M, xi, Ab);
        init_h0<<<16, 256, 0, stream>>>(hidden, houts);
        for (int t = 1; t <= TT; t++)
            step1<<<NN / 8, 512, 0, stream>>>(Ab, tempTf + (size_t)(t - 1) * NN,
                                              houts + (size_t)(t - 1) * NN,
                                              houts + (size_t)t * NN);
        emit<<<(240 * NN + NN) / 256, 256, 0, stream>>>(houts, out);
    }
}